// Round 1
// baseline (458.841 us; speedup 1.0000x reference)
//
#include <hip/hip_runtime.h>

// PWC-Net correlation, 9x9 displacement grid.
// out[b, dy*9+dx, y, x] = (1/C) * sum_c F[b,c,y,x] * S[b,c,y+dy-4,x+dx-4] (S zero-padded)
//
// Structure: block = (batch b, y-slab of YT=8 rows, fixed dy).
//  - acc[8 px][9 dx] per thread (72 VGPRs), dy fixed per block so every output
//    is written exactly once, no cross-block reduction.
//  - second rows (8 consecutive + x-halo, zero-padded) staged in LDS per
//    8-channel chunk, [c][r][x'] layout, all accesses aligned float4.
//  - first read directly from global (1x per block; 9x dy re-read served by
//    L2/L3 -- grid swizzled so blockIdx%8 = batch -> per-XCD batch isolation,
//    dy innermost -> 9 consecutive same-XCD blocks share first rows + sliding
//    second-row window).

namespace {
constexpr int kB = 8;
constexpr int kC = 128;
constexpr int kH = 112;
constexpr int kW = 192;
constexpr int kD = 4;            // max displacement
constexpr int kKD = 9;           // 2*kD+1
constexpr int kHW = kH * kW;     // 21504
constexpr long long kCHW = (long long)kC * kHW;

constexpr int YT = 8;            // output rows per block
constexpr int CCK = 8;           // channels per LDS chunk
constexpr int XS = kW + 2 * kD;  // 200: staged second row width (with halo)
constexpr int PX = 8;            // pixels per thread along x
constexpr int XG = kW / PX;      // 24 x-groups
constexpr int NT = XG * YT;      // 192 threads = 3 waves
constexpr int NQ = CCK * YT * (XS / 4);  // 3200 staged quads per chunk
}  // namespace

__global__ __launch_bounds__(NT, 2)
void corr81_kernel(const float* __restrict__ first,
                   const float* __restrict__ second,
                   float* __restrict__ out) {
  __shared__ float sS[CCK * YT * XS];  // 51.2 KB -> 3 blocks/CU

  const int g = blockIdx.x;
  const int b = g & 7;             // batch -> XCD slab (blockIdx % 8 heuristic)
  const int i = g >> 3;
  const int dy = i % kKD;          // dy innermost on each XCD: L2 reuse
  const int y0 = (i / kKD) * YT;

  const int tid = threadIdx.x;
  const int xg = tid % XG;
  const int yl = tid / XG;
  const int px0 = xg * PX;
  const int ys0 = y0 + dy - kD;    // first staged second row (may be <0)

  const float* fbase = first + (long long)b * kCHW + (long long)(y0 + yl) * kW + px0;
  const float* sbase = second + (long long)b * kCHW;

  float acc[PX][kKD];
#pragma unroll
  for (int p = 0; p < PX; ++p)
#pragma unroll
    for (int d = 0; d < kKD; ++d) acc[p][d] = 0.0f;

  for (int ch = 0; ch < kC / CCK; ++ch) {
    const int c0 = ch * CCK;

    // ---- stage second tile [c][r][x'] (x' = global x + 4, zero halo) ----
    for (int k = tid; k < NQ; k += NT) {
      const int q = k % (XS / 4);      // quad within row: 0..49
      const int cr = k / (XS / 4);
      const int xp = q * 4;            // x' of quad start
      const int r = cr % YT;
      const int c = cr / YT;
      const int ys = ys0 + r;
      float4 v = make_float4(0.f, 0.f, 0.f, 0.f);
      // interior quads map to aligned global quads at gx = xp-4; edge quads
      // (xp==0 or xp==196) are fully out of bounds -> zeros.
      if ((unsigned)ys < (unsigned)kH && xp >= 4 && xp <= kW) {
        v = *(const float4*)(sbase + (long long)(c0 + c) * kHW +
                             (long long)ys * kW + (xp - 4));
      }
      *(float4*)&sS[(c * YT + r) * XS + xp] = v;
    }
    __syncthreads();

    // ---- compute: per channel, 2 global dwordx4 + 4 ds_read_b128 + 72 FMA ----
#pragma unroll
    for (int cc = 0; cc < CCK; ++cc) {
      const float* fp = fbase + (long long)(c0 + cc) * kHW;
      const float4 fq0 = *(const float4*)(fp);
      const float4 fq1 = *(const float4*)(fp + 4);
      const float* sp = &sS[(cc * YT + yl) * XS + px0];
      const float4 s0 = *(const float4*)(sp);
      const float4 s1 = *(const float4*)(sp + 4);
      const float4 s2 = *(const float4*)(sp + 8);
      const float4 s3 = *(const float4*)(sp + 12);
      const float fa[PX] = {fq0.x, fq0.y, fq0.z, fq0.w,
                            fq1.x, fq1.y, fq1.z, fq1.w};
      const float sw[16] = {s0.x, s0.y, s0.z, s0.w, s1.x, s1.y, s1.z, s1.w,
                            s2.x, s2.y, s2.z, s2.w, s3.x, s3.y, s3.z, s3.w};
#pragma unroll
      for (int p = 0; p < PX; ++p)
#pragma unroll
        for (int d = 0; d < kKD; ++d)
          acc[p][d] = fmaf(fa[p], sw[p + d], acc[p][d]);
    }
    __syncthreads();
  }

  // ---- epilogue: 9 dx channels x 8 px, coalesced dwordx4 stores ----
  const float scale = 1.0f / (float)kC;
  float* obase = out + ((long long)b * 81 + (long long)dy * kKD) * kHW +
                 (long long)(y0 + yl) * kW + px0;
#pragma unroll
  for (int d = 0; d < kKD; ++d) {
    float4 o0 = make_float4(acc[0][d] * scale, acc[1][d] * scale,
                            acc[2][d] * scale, acc[3][d] * scale);
    float4 o1 = make_float4(acc[4][d] * scale, acc[5][d] * scale,
                            acc[6][d] * scale, acc[7][d] * scale);
    float* op = obase + (long long)d * kHW;
    *(float4*)op = o0;
    *(float4*)(op + 4) = o1;
  }
}

extern "C" void kernel_launch(void* const* d_in, const int* in_sizes, int n_in,
                              void* d_out, int out_size, void* d_ws, size_t ws_size,
                              hipStream_t stream) {
  const float* first = (const float*)d_in[0];
  const float* second = (const float*)d_in[1];
  float* out = (float*)d_out;

  const int grid = kB * (kH / YT) * kKD;  // 8 * 14 * 9 = 1008 blocks
  corr81_kernel<<<grid, NT, 0, stream>>>(first, second, out);
}

// Round 2
// 331.234 us; speedup vs baseline: 1.3852x; 1.3852x over previous
//
#include <hip/hip_runtime.h>

// PWC-Net 9x9 correlation, direct-register version (no LDS, no barriers).
// out[b, dy*9+dx, y, x] = (1/C) * sum_c F[b,c,y,x] * S[b,c,y+dy-4,x+dx-4]
//
// Thread = (b, y, dy, xg): owns PX=8 pixels x 9 dx accumulators (72 VGPR).
// Per channel: 2 global f4 (first) + 4 global f4 (second window, 16B-aligned)
// + 72 FMA. Window halos beyond the image x-range come from a zero-filled
// __device__ array selected by thread-constant pointers (stride 0), so there
// is no per-channel masking VALU and no OOB access. Rows ys outside [0,H)
// skip the loop entirely and write zeros.
// Grid: b = blockIdx%8 (XCD slab), dy innermost -> sliding L2 window.
// 1008 blocks x 3 waves ~ 11.8 waves/CU; VGPR<=128 gives 16 waves/CU
// capacity -> whole grid co-resident, zero tail.

namespace {
constexpr int kC = 128;
constexpr int kH = 112;
constexpr int kW = 192;
constexpr int kD = 4;            // max displacement
constexpr int kKD = 9;           // 2*kD+1
constexpr int kHW = kH * kW;     // 21504
constexpr long long kCHW = (long long)kC * kHW;

constexpr int PX = 8;            // pixels per thread along x
constexpr int XG = kW / PX;      // 24 x-groups
constexpr int YT = 8;            // rows per block
constexpr int NT = XG * YT;      // 192 threads = 3 waves
}  // namespace

__device__ __attribute__((aligned(16))) float g_zeros[4] = {0.f, 0.f, 0.f, 0.f};

__global__ __launch_bounds__(NT, 4)
void corr81_kernel(const float* __restrict__ first,
                   const float* __restrict__ second,
                   float* __restrict__ out) {
  const int g = blockIdx.x;
  const int b = g & 7;             // batch -> XCD slab
  const int i = g >> 3;
  const int dy = i % kKD;          // dy innermost: L2 sliding window
  const int y0 = (i / kKD) * YT;

  const int tid = threadIdx.x;
  const int xg = tid % XG;
  const int yl = tid / XG;
  const int px0 = xg * PX;
  const int y = y0 + yl;
  const int ys = y + dy - kD;      // second row for this dy (may be OOB)

  float acc[PX][kKD];
#pragma unroll
  for (int p = 0; p < PX; ++p)
#pragma unroll
    for (int d = 0; d < kKD; ++d) acc[p][d] = 0.0f;

  if ((unsigned)ys < (unsigned)kH) {
    const bool left = (xg == 0);          // window [-4,0) is zero padding
    const bool right = (xg == XG - 1);    // window [192,196) is zero padding

    const float* fp = first + (long long)b * kCHW + (long long)y * kW + px0;
    const float* sp = second + (long long)b * kCHW + (long long)ys * kW + px0;
    const float* pw0 = left ? g_zeros : (sp - 4);   // window floats [0,4)
    const float* pw3 = right ? g_zeros : (sp + 8);  // window floats [12,16)
    const long long st0 = left ? 0 : kHW;
    const long long st3 = right ? 0 : kHW;

    for (int c = 0; c < kC; ++c) {
      const float4 f0 = *(const float4*)(fp);
      const float4 f1 = *(const float4*)(fp + 4);
      const float4 w0 = *(const float4*)(pw0);
      const float4 w1 = *(const float4*)(sp);       // window floats [4,8)
      const float4 w2 = *(const float4*)(sp + 4);   // window floats [8,12)
      const float4 w3 = *(const float4*)(pw3);

      const float fa[PX] = {f0.x, f0.y, f0.z, f0.w, f1.x, f1.y, f1.z, f1.w};
      const float sw[16] = {w0.x, w0.y, w0.z, w0.w, w1.x, w1.y, w1.z, w1.w,
                            w2.x, w2.y, w2.z, w2.w, w3.x, w3.y, w3.z, w3.w};
#pragma unroll
      for (int p = 0; p < PX; ++p)
#pragma unroll
        for (int d = 0; d < kKD; ++d)
          acc[p][d] = fmaf(fa[p], sw[p + d], acc[p][d]);

      fp += kHW;
      sp += kHW;
      pw0 += st0;
      pw3 += st3;
    }
  }

  // epilogue: 9 dx channels x 8 px, coalesced dwordx4 stores (zeros if ys OOB)
  const float scale = 1.0f / (float)kC;
  float* obase = out + ((long long)b * 81 + (long long)dy * kKD) * kHW +
                 (long long)y * kW + px0;
#pragma unroll
  for (int d = 0; d < kKD; ++d) {
    float4 o0 = make_float4(acc[0][d] * scale, acc[1][d] * scale,
                            acc[2][d] * scale, acc[3][d] * scale);
    float4 o1 = make_float4(acc[4][d] * scale, acc[5][d] * scale,
                            acc[6][d] * scale, acc[7][d] * scale);
    float* op = obase + (long long)d * kHW;
    *(float4*)op = o0;
    *(float4*)(op + 4) = o1;
  }
}

extern "C" void kernel_launch(void* const* d_in, const int* in_sizes, int n_in,
                              void* d_out, int out_size, void* d_ws, size_t ws_size,
                              hipStream_t stream) {
  const float* first = (const float*)d_in[0];
  const float* second = (const float*)d_in[1];
  float* out = (float*)d_out;

  const int grid = 8 * (kH / YT) * kKD;  // 8 * 14 * 9 = 1008 blocks
  corr81_kernel<<<grid, NT, 0, stream>>>(first, second, out);
}